// Round 1
// baseline (200.235 us; speedup 1.0000x reference)
//
#include <hip/hip_runtime.h>
#include <math.h>

#define NT_ 365
#define NS_ 1024
#define NH_ 64
#define NG_ 32
#define NW_ 514  // NH*8 + 2

// ---------------- wave64 sum reduction via DPP (result in lane 63) ----------
template<int CTRL>
__device__ __forceinline__ float dpp_add(float x) {
  // old = 0, full row/bank masks, bound_ctrl=true (OOB lanes contribute 0)
  int t = __builtin_amdgcn_update_dpp(0, __float_as_int(x), CTRL, 0xf, 0xf, true);
  return x + __int_as_float(t);
}

__device__ __forceinline__ float wave_sum64(float x) {
  x = dpp_add<0x111>(x); // row_shr:1
  x = dpp_add<0x112>(x); // row_shr:2
  x = dpp_add<0x114>(x); // row_shr:4
  x = dpp_add<0x118>(x); // row_shr:8  -> lane15 of each row = row sum
  x = dpp_add<0x142>(x); // row_bcast:15
  x = dpp_add<0x143>(x); // row_bcast:31 -> lane 63 = total
  return x;
}

// ---------------- rain/snow partition + met transform -----------------------
struct Met { float Ps, Pl, Ta, E; };

__device__ __forceinline__ Met compute_met(float4 xv) {
  Met m;
  const float P = xv.x;
  m.E = xv.y;
  const float T1 = xv.z, T2 = xv.w;
  m.Ta = (T1 + T2) * 0.5f;
  float rP;
  // reference: rP=1-acos(clip)/3.1415, then where(T1>=0 ->1), where(T2<=0 ->0)
  // precedence: T2<=0 wins, then T1>=0, else the acos path (valid region).
  if (T2 <= 0.0f) {
    rP = 0.0f;
  } else if (T1 >= 0.0f) {
    rP = 1.0f;
  } else {
    float r = (T1 + T2) / (T2 - T1);
    r = fminf(fmaxf(r, -0.999999f), 0.999999f);
    rP = 1.0f - acosf(r) * (1.0f / 3.1415f);
  }
  m.Pl = rP * P;
  m.Ps = (1.0f - rP) * P;
  return m;
}

__device__ __forceinline__ float sigmoidf(float v) {
  return 1.0f / (1.0f + expf(-v));
}

// one wave (64 lanes) per site; lane = hidden unit
__global__ __launch_bounds__(256) void waternet_scan(
    const float* __restrict__ x,     // [NT, NS, 4]
    const float* __restrict__ xc,    // [NS, NG]
    const float* __restrict__ fc_w,  // [NW, NG]
    const float* __restrict__ fc_b,  // [NW]
    float* __restrict__ out)         // [NT, NS]
{
  const int tid  = threadIdx.x;
  const int lane = tid & 63;
  const int site = ((blockIdx.x << 8) + tid) >> 6;   // 4 sites per block
  const int us   = __builtin_amdgcn_readfirstlane(site); // wave-uniform site id

  // ---- prologue: w[site, j] = xc[site,:] . fc_w[j,:] + fc_b[j],
  //      j = k*64 + lane for k=0..7, plus j = 513 (qb row, lane-uniform)
  float acc[8];
#pragma unroll
  for (int k = 0; k < 8; ++k) acc[k] = fc_b[k * NH_ + lane];
  float accq = fc_b[NW_ - 1];

  const float4* xcq = (const float4*)(xc + us * NG_);
  const float4* wq4 = (const float4*)fc_w;
#pragma unroll
  for (int g4 = 0; g4 < NG_ / 4; ++g4) {
    const float4 xv = xcq[g4];                 // uniform (broadcast) load
#pragma unroll
    for (int k = 0; k < 8; ++k) {
      const float4 w = wq4[(k * NH_ + lane) * (NG_ / 4) + g4];
      acc[k] = fmaf(xv.x, w.x, acc[k]);
      acc[k] = fmaf(xv.y, w.y, acc[k]);
      acc[k] = fmaf(xv.z, w.z, acc[k]);
      acc[k] = fmaf(xv.w, w.w, acc[k]);
    }
    {
      const float4 w = wq4[(NW_ - 1) * (NG_ / 4) + g4];  // uniform row
      accq = fmaf(xv.x, w.x, accq);
      accq = fmaf(xv.y, w.y, accq);
      accq = fmaf(xv.z, w.z, accq);
      accq = fmaf(xv.w, w.w, accq);
    }
  }

  // ---- gates
  const float gm = expf(acc[0]) + 1.0f;
  const float ge = sigmoidf(acc[1]) * 2.0f;
  const float go = sigmoidf(acc[2]);
  const float gl = expf(acc[3] * 2.0f);
  // softmax over the 64 lanes (hidden dim)
  float mx = acc[4];
#pragma unroll
  for (int mm = 32; mm >= 1; mm >>= 1) mx = fmaxf(mx, __shfl_xor(mx, mm, 64));
  const float ex = expf(acc[4] - mx);
  float sm = ex;
#pragma unroll
  for (int mm = 32; mm >= 1; mm >>= 1) sm += __shfl_xor(sm, mm, 64);
  const float ga = ex / sm;
  const float gb = sigmoidf(acc[5]);
  const float kb = sigmoidf(acc[6]) * 0.1f;
  const float gi = sigmoidf(acc[7]);
  const float qb = fmaxf(accq, 0.0f) * (1.0f / NH_);
  const float kb1m    = 1.0f - kb;          // G0n = G * (1-kb)
  const float gb1m_ga = (1.0f - gb) * ga;   // Q2 contribution folded

  // ---- the 365-step serial scan
  float S0 = 0.0f, H0 = 0.0f, G0 = 0.0f;
  const float4* xp = (const float4*)x;       // [NT][NS] of float4

  Met m = compute_met(xp[site]);             // t = 0

  auto step = [&](int t, const Met& mt) {
    const float S    = S0 + mt.Ps;
    const float melt = (mt.Ta > 0.0f) ? mt.Ta * gm : 0.0f; // relu(Ta*gm), gm>0
    const float Sm   = fminf(S0, melt);
    const float addin = fmaf(mt.Pl, gi, -mt.E * ge);       // Pl*gi - E*ge
    const float H    = fmaxf(H0 + Sm + addin, 0.0f);
    const float Q1   = fmaxf(H - gl, 0.0f);
    const float Q2a  = fminf(H, gl) * go;
    const float G    = fmaf(Q2a, gb, G0);
    const float Q3   = G * kb;
    H0 = fminf(H - Q2a, gl);
    G0 = G * kb1m;
    S0 = S - Sm;
    const float y   = fmaf(Q1 + Q3, ga, Q2a * gb1m_ga);    // (Q1+Q2+Q3)*ga
    const float tot = wave_sum64(y);                       // off critical path
    if (lane == 63) out[t * NS_ + site] = tot + qb;        // qb*sum(ga)=qb
  };

  for (int t = 0; t < NT_ - 1; ++t) {
    const float4 xn = xp[(t + 1) * NS_ + site];  // prefetch next step
    step(t, m);
    m = compute_met(xn);                          // independent of recurrence
  }
  step(NT_ - 1, m);
}

extern "C" void kernel_launch(void* const* d_in, const int* in_sizes, int n_in,
                              void* d_out, int out_size, void* d_ws, size_t ws_size,
                              hipStream_t stream) {
  const float* x    = (const float*)d_in[0];
  const float* xc   = (const float*)d_in[1];
  const float* fc_w = (const float*)d_in[2];
  const float* fc_b = (const float*)d_in[3];
  float* out = (float*)d_out;

  // 1024 sites, one wave each; 256 threads = 4 sites per block -> 256 blocks
  hipLaunchKernelGGL(waternet_scan, dim3(NS_ / 4), dim3(256), 0, stream,
                     x, xc, fc_w, fc_b, out);
}

// Round 2
// 108.493 us; speedup vs baseline: 1.8456x; 1.8456x over previous
//
#include <hip/hip_runtime.h>
#include <math.h>

#define NT_ 365
#define NS_ 1024
#define NH_ 64
#define NG_ 32
#define NW_ 514  // NH*8 + 2
#define CH_ 64   // timesteps staged per chunk (= wave size)
#define NCHUNK_ ((NT_ + CH_ - 1) / CH_)  // 6

// ---------------- wave64 sum reduction via DPP (result in lane 63) ----------
template<int CTRL>
__device__ __forceinline__ float dpp_add(float x) {
  int t = __builtin_amdgcn_update_dpp(0, __float_as_int(x), CTRL, 0xf, 0xf, true);
  return x + __int_as_float(t);
}

__device__ __forceinline__ float wave_sum64(float x) {
  x = dpp_add<0x111>(x); // row_shr:1
  x = dpp_add<0x112>(x); // row_shr:2
  x = dpp_add<0x114>(x); // row_shr:4
  x = dpp_add<0x118>(x); // row_shr:8  -> lane15 of each row = row sum
  x = dpp_add<0x142>(x); // row_bcast:15
  x = dpp_add<0x143>(x); // row_bcast:31 -> lane 63 = total
  return x;
}

// ---------------- rain/snow partition + met transform -----------------------
// returns (Ps, Pl, relu(Ta), E) — relu folded here since gm > 0
__device__ __forceinline__ float4 compute_met(float4 xv) {
  const float P = xv.x, E = xv.y, T1 = xv.z, T2 = xv.w;
  const float Ta = (T1 + T2) * 0.5f;
  float rP;
  if (T2 <= 0.0f) {
    rP = 0.0f;
  } else if (T1 >= 0.0f) {
    rP = 1.0f;
  } else {
    float r = (T1 + T2) / (T2 - T1);
    r = fminf(fmaxf(r, -0.999999f), 0.999999f);
    rP = 1.0f - acosf(r) * (1.0f / 3.1415f);
  }
  float4 m;
  m.x = (1.0f - rP) * P;     // Ps
  m.y = rP * P;              // Pl
  m.z = fmaxf(Ta, 0.0f);     // relu(Ta)
  m.w = E;
  return m;
}

__device__ __forceinline__ float sigmoidf(float v) {
  return 1.0f / (1.0f + expf(-v));
}

// one wave (64 lanes) per site; lane = hidden unit
__global__ __launch_bounds__(256) void waternet_scan(
    const float* __restrict__ x,     // [NT, NS, 4]
    const float* __restrict__ xc,    // [NS, NG]
    const float* __restrict__ fc_w,  // [NW, NG]
    const float* __restrict__ fc_b,  // [NW]
    float* __restrict__ out)         // [NT, NS]
{
  __shared__ float4 smet[4][2][CH_];  // [wave][buf][step] — per-wave, no barriers

  const int tid  = threadIdx.x;
  const int lane = tid & 63;
  const int wv   = tid >> 6;
  const int site = (blockIdx.x << 2) + wv;
  const int us   = __builtin_amdgcn_readfirstlane(site);

  // ---- prologue: w[site, j] = xc[site,:] . fc_w[j,:] + fc_b[j]
  float acc[8];
#pragma unroll
  for (int k = 0; k < 8; ++k) acc[k] = fc_b[k * NH_ + lane];
  float accq = fc_b[NW_ - 1];

  const float4* xcq = (const float4*)(xc + us * NG_);
  const float4* wq4 = (const float4*)fc_w;
#pragma unroll
  for (int g4 = 0; g4 < NG_ / 4; ++g4) {
    const float4 xv = xcq[g4];
#pragma unroll
    for (int k = 0; k < 8; ++k) {
      const float4 w = wq4[(k * NH_ + lane) * (NG_ / 4) + g4];
      acc[k] = fmaf(xv.x, w.x, acc[k]);
      acc[k] = fmaf(xv.y, w.y, acc[k]);
      acc[k] = fmaf(xv.z, w.z, acc[k]);
      acc[k] = fmaf(xv.w, w.w, acc[k]);
    }
    {
      const float4 w = wq4[(NW_ - 1) * (NG_ / 4) + g4];
      accq = fmaf(xv.x, w.x, accq);
      accq = fmaf(xv.y, w.y, accq);
      accq = fmaf(xv.z, w.z, accq);
      accq = fmaf(xv.w, w.w, accq);
    }
  }

  // ---- gates
  const float gm = expf(acc[0]) + 1.0f;
  const float ge = sigmoidf(acc[1]) * 2.0f;
  const float go = sigmoidf(acc[2]);
  const float gl = expf(acc[3] * 2.0f);
  float mx = acc[4];
#pragma unroll
  for (int mm = 32; mm >= 1; mm >>= 1) mx = fmaxf(mx, __shfl_xor(mx, mm, 64));
  const float ex = expf(acc[4] - mx);
  float sm = ex;
#pragma unroll
  for (int mm = 32; mm >= 1; mm >>= 1) sm += __shfl_xor(sm, mm, 64);
  const float ga = ex / sm;
  const float gb = sigmoidf(acc[5]);
  const float kb = sigmoidf(acc[6]) * 0.1f;
  const float gi = sigmoidf(acc[7]);
  const float qb = fmaxf(accq, 0.0f) * (1.0f / NH_);
  const float kb1m    = 1.0f - kb;
  const float gb1m_ga = (1.0f - gb) * ga;

  // ---- the 365-step serial scan, staged through LDS in 64-step chunks
  float S0 = 0.0f, H0 = 0.0f, G0 = 0.0f;
  const float4* xp = (const float4*)x;  // [NT][NS] of float4

  auto load_chunk = [&](int c) -> float4 {
    const int t = c * CH_ + lane;       // per-lane timestep
    if (t < NT_) return xp[t * NS_ + site];
    return make_float4(0.0f, 0.0f, 0.0f, 0.0f);
  };

  auto step = [&](int t, float4 mt) {   // mt = (Ps, Pl, reluTa, E)
    const float S     = S0 + mt.x;
    const float melt  = mt.z * gm;                     // relu(Ta)*gm
    const float Sm    = fminf(S0, melt);
    const float addin = fmaf(mt.y, gi, -mt.w * ge);    // Pl*gi - E*ge
    const float H     = fmaxf(H0 + Sm + addin, 0.0f);
    const float Q1    = fmaxf(H - gl, 0.0f);
    const float Q2a   = fminf(H, gl) * go;
    const float G     = fmaf(Q2a, gb, G0);
    const float Q3    = G * kb;
    H0 = fminf(H - Q2a, gl);
    G0 = G * kb1m;
    S0 = S - Sm;
    const float y   = fmaf(Q1 + Q3, ga, Q2a * gb1m_ga);
    const float tot = wave_sum64(y);                   // off critical path
    if (lane == 63) out[t * NS_ + site] = tot + qb;
  };

  // prime chunk 0
  smet[wv][0][lane] = compute_met(load_chunk(0));
  int buf = 0;

  for (int c = 0; c < NCHUNK_; ++c) {
    float4 xnext;
    const bool more = (c + 1 < NCHUNK_);
    if (more) xnext = load_chunk(c + 1);   // single global load, in flight all chunk

    const int base = c * CH_;
    const int len  = (NT_ - base < CH_) ? (NT_ - base) : CH_;
    if (len == CH_) {
      for (int j0 = 0; j0 < CH_; j0 += 8) {
        float4 mm[8];
#pragma unroll
        for (int u = 0; u < 8; ++u) mm[u] = smet[wv][buf][j0 + u];  // uniform bcast reads
#pragma unroll
        for (int u = 0; u < 8; ++u) step(base + j0 + u, mm[u]);
      }
    } else {
      for (int j = 0; j < len; ++j) step(base + j, smet[wv][buf][j]);
    }

    if (more) {
      smet[wv][buf ^ 1][lane] = compute_met(xnext);  // parallel met transform
      buf ^= 1;
    }
  }
}

extern "C" void kernel_launch(void* const* d_in, const int* in_sizes, int n_in,
                              void* d_out, int out_size, void* d_ws, size_t ws_size,
                              hipStream_t stream) {
  const float* x    = (const float*)d_in[0];
  const float* xc   = (const float*)d_in[1];
  const float* fc_w = (const float*)d_in[2];
  const float* fc_b = (const float*)d_in[3];
  float* out = (float*)d_out;

  hipLaunchKernelGGL(waternet_scan, dim3(NS_ / 4), dim3(256), 0, stream,
                     x, xc, fc_w, fc_b, out);
}

// Round 3
// 90.660 us; speedup vs baseline: 2.2086x; 1.1967x over previous
//
#include <hip/hip_runtime.h>
#include <math.h>

#define NT_ 365
#define NS_ 1024
#define NH_ 64
#define NG_ 32
#define NW_ 514        // NH*8 + 2
#define CH_ 64         // timesteps per chunk (= wave size)
#define NCHUNK_ 6      // ceil(365/64); tail steps are harmless dummies
#define YPAD_ 65       // padded row stride (floats): bank = (t+lane)%32, conflict-free

__device__ __forceinline__ float sigmoidf(float v) {
  return 1.0f / (1.0f + expf(-v));
}

// broadcast lane j's value to all lanes (VALU pipe, no LDS)
__device__ __forceinline__ float blane(float v, int j) {
  return __int_as_float(__builtin_amdgcn_readlane(__float_as_int(v), j));
}

struct Met { float Ps, Pl, Tr, E; };  // Tr = relu(Ta), gm>0 lets us fold the relu

__device__ __forceinline__ Met compute_met(float4 xv) {
  const float P = xv.x, E = xv.y, T1 = xv.z, T2 = xv.w;
  const float Ta = (T1 + T2) * 0.5f;
  float rP;
  if (T2 <= 0.0f) {
    rP = 0.0f;
  } else if (T1 >= 0.0f) {
    rP = 1.0f;
  } else {
    float r = (T1 + T2) / (T2 - T1);
    r = fminf(fmaxf(r, -0.999999f), 0.999999f);
    rP = 1.0f - acosf(r) * (1.0f / 3.1415f);
  }
  Met m;
  m.Ps = (1.0f - rP) * P;
  m.Pl = rP * P;
  m.Tr = fmaxf(Ta, 0.0f);
  m.E  = E;
  return m;
}

// one wave (64 lanes) per site; lane = hidden unit; met staged lane = timestep
__global__ __launch_bounds__(256) void waternet_scan(
    const float* __restrict__ x,     // [NT, NS, 4]
    const float* __restrict__ xc,    // [NS, NG]
    const float* __restrict__ fc_w,  // [NW, NG]
    const float* __restrict__ fc_b,  // [NW]
    float* __restrict__ out)         // [NT, NS]
{
  __shared__ float ytile[4][CH_ * YPAD_];  // 66.6 KB; per-wave slices, no barriers

  const int tid  = threadIdx.x;
  const int lane = tid & 63;
  const int wv   = tid >> 6;
  const int site = (blockIdx.x << 2) + wv;
  const int us   = __builtin_amdgcn_readfirstlane(site);
  const float4* xp = (const float4*)x;  // [NT][NS] of float4

  // ---- chunk-0 prefetch issued first: HBM latency hides under the gate GEMM
  float4 xcur = xp[lane * NS_ + site];  // t = lane (< 365 always)

  // ---- prologue GEMM: w[site, j] = xc[site,:] . fc_w[j,:] + fc_b[j]
  float acc[8];
#pragma unroll
  for (int k = 0; k < 8; ++k) acc[k] = fc_b[k * NH_ + lane];
  float accq = fc_b[NW_ - 1];

  const float4* xcq = (const float4*)(xc + us * NG_);
  const float4* wq4 = (const float4*)fc_w;
#pragma unroll
  for (int g4 = 0; g4 < NG_ / 4; ++g4) {
    const float4 xv = xcq[g4];
#pragma unroll
    for (int k = 0; k < 8; ++k) {
      const float4 w = wq4[(k * NH_ + lane) * (NG_ / 4) + g4];
      acc[k] = fmaf(xv.x, w.x, acc[k]);
      acc[k] = fmaf(xv.y, w.y, acc[k]);
      acc[k] = fmaf(xv.z, w.z, acc[k]);
      acc[k] = fmaf(xv.w, w.w, acc[k]);
    }
    {
      const float4 w = wq4[(NW_ - 1) * (NG_ / 4) + g4];
      accq = fmaf(xv.x, w.x, accq);
      accq = fmaf(xv.y, w.y, accq);
      accq = fmaf(xv.z, w.z, accq);
      accq = fmaf(xv.w, w.w, accq);
    }
  }

  // ---- gates (per-lane = per hidden unit)
  const float gm = expf(acc[0]) + 1.0f;
  const float ge = sigmoidf(acc[1]) * 2.0f;
  const float go = sigmoidf(acc[2]);
  const float gl = expf(acc[3] * 2.0f);
  float mx = acc[4];
#pragma unroll
  for (int mm = 32; mm >= 1; mm >>= 1) mx = fmaxf(mx, __shfl_xor(mx, mm, 64));
  const float ex = expf(acc[4] - mx);
  float sm = ex;
#pragma unroll
  for (int mm = 32; mm >= 1; mm >>= 1) sm += __shfl_xor(sm, mm, 64);
  const float ga = ex / sm;
  const float gb = sigmoidf(acc[5]);
  const float kb = sigmoidf(acc[6]) * 0.1f;
  const float gi = sigmoidf(acc[7]);
  const float qb = fmaxf(accq, 0.0f) * (1.0f / NH_);
  const float kb1m    = 1.0f - kb;          // G0n = G*(1-kb)
  const float gb1m_ga = (1.0f - gb) * ga;   // Q2 contribution folded
  const float nge     = -ge;                // addin = Pl*gi + E*(-ge)

  // ---- the scan: 6 chunks x 64 steps (dummy tail steps don't affect outputs)
  float S0 = 0.0f, H0 = 0.0f, G0 = 0.0f;
  Met m = compute_met(xcur);                // lane = local timestep

  float*       yw = &ytile[wv][lane];         // step writes yw[t*YPAD_]
  const float* yr = &ytile[wv][lane * YPAD_]; // epilogue: lane sums its row
  float* outp = out + lane * NS_ + site;      // out[(c*64+lane)*NS + site]

  for (int c = 0; c < NCHUNK_; ++c) {
    float4 xnext;
    const bool more = (c + 1 < NCHUNK_);
    if (more) {
      const int t = (c + 1) * CH_ + lane;
      xnext = (t < NT_) ? xp[t * NS_ + site]
                        : make_float4(0.0f, 0.0f, 0.0f, 0.0f);
    }

#pragma unroll
    for (int j = 0; j < CH_; ++j) {
      // broadcast step-j met from lane j (SGPR results, VALU-pipe only)
      const float Ps = blane(m.Ps, j);
      const float Pl = blane(m.Pl, j);
      const float Tr = blane(m.Tr, j);
      const float E  = blane(m.E,  j);

      const float S     = S0 + Ps;
      const float Sm    = fminf(S0, Tr * gm);
      const float addin = fmaf(E, nge, Pl * gi);
      const float H     = fmaxf(H0 + Sm + addin, 0.0f);
      const float M     = fminf(H, gl);
      const float Q1    = H - M;                 // == relu(H - gl)
      const float Q2a   = M * go;
      const float G     = fmaf(Q2a, gb, G0);
      const float Q3    = G * kb;
      H0 = fminf(H - Q2a, gl);
      G0 = G * kb1m;
      S0 = S - Sm;
      yw[j * YPAD_] = fmaf(Q1 + Q3, ga, Q2a * gb1m_ga);  // immediate-offset ds_write
    }

    // transposed reduction: lane t' sums row t' (conflict-free: bank=(t'+h)%32)
    float t0 = 0.0f, t1 = 0.0f, t2 = 0.0f, t3 = 0.0f;
#pragma unroll
    for (int h = 0; h < CH_; h += 4) {
      t0 += yr[h + 0];
      t1 += yr[h + 1];
      t2 += yr[h + 2];
      t3 += yr[h + 3];
    }
    const float tot = (t0 + t1) + (t2 + t3);
    const int t_out = c * CH_ + lane;
    if (t_out < NT_) *outp = tot + qb;   // qb * sum(ga) == qb
    outp += CH_ * NS_;

    if (more) m = compute_met(xnext);    // parallel met transform, off-chain
  }
}

extern "C" void kernel_launch(void* const* d_in, const int* in_sizes, int n_in,
                              void* d_out, int out_size, void* d_ws, size_t ws_size,
                              hipStream_t stream) {
  const float* x    = (const float*)d_in[0];
  const float* xc   = (const float*)d_in[1];
  const float* fc_w = (const float*)d_in[2];
  const float* fc_b = (const float*)d_in[3];
  float* out = (float*)d_out;

  hipLaunchKernelGGL(waternet_scan, dim3(NS_ / 4), dim3(256), 0, stream,
                     x, xc, fc_w, fc_b, out);
}

// Round 4
// 90.212 us; speedup vs baseline: 2.2196x; 1.0050x over previous
//
#include <hip/hip_runtime.h>
#include <math.h>

#define NT_ 365
#define NS_ 1024
#define NH_ 64
#define NG_ 32
#define NW_ 514        // NH*8 + 2
#define CH_ 64         // timesteps per chunk (= wave size)
#define NCHUNK_ 6      // ceil(365/64)
#define YPAD_ 65       // padded row stride: bank = (lane+j)%32, conflict-free R/W

__device__ __forceinline__ float sigmoidf(float v) {
  return 1.0f / (1.0f + expf(-v));
}

// met = (Ps, Pl, relu(Ta), E); relu folded here since gm > 0
__device__ __forceinline__ float4 compute_met(float4 xv) {
  const float P = xv.x, E = xv.y, T1 = xv.z, T2 = xv.w;
  const float Ta = (T1 + T2) * 0.5f;
  float rP;
  if (T2 <= 0.0f) {
    rP = 0.0f;
  } else if (T1 >= 0.0f) {
    rP = 1.0f;
  } else {
    float r = (T1 + T2) / (T2 - T1);
    r = fminf(fmaxf(r, -0.999999f), 0.999999f);
    rP = 1.0f - acosf(r) * (1.0f / 3.1415f);
  }
  float4 m;
  m.x = (1.0f - rP) * P;   // Ps
  m.y = rP * P;            // Pl
  m.z = fmaxf(Ta, 0.0f);   // relu(Ta)
  m.w = E;
  return m;
}

// one wave (64 lanes) per site; lane = hidden unit; met staged lane = timestep
__global__ __launch_bounds__(256) void waternet_scan(
    const float* __restrict__ x,     // [NT, NS, 4]
    const float* __restrict__ xc,    // [NS, NG]
    const float* __restrict__ fc_w,  // [NW, NG]
    const float* __restrict__ fc_b,  // [NW]
    float* __restrict__ out)         // [NT, NS]
{
  __shared__ float  ytile[4][2][CH_ * YPAD_]; // 133 KB, per-wave slices
  __shared__ float4 smet[4][CH_];             // 4 KB, per-wave met buffer

  const int tid  = threadIdx.x;
  const int lane = tid & 63;
  const int wv   = tid >> 6;
  const int site = (blockIdx.x << 2) + wv;
  const int us   = __builtin_amdgcn_readfirstlane(site);
  const float4* xp = (const float4*)x;

  // chunk-0 prefetch first: HBM latency hides under the gate GEMM
  float4 xcur = xp[lane * NS_ + site];  // t = lane

  // ---- prologue GEMM: w[site, j] = xc[site,:] . fc_w[j,:] + fc_b[j]
  float acc[8];
#pragma unroll
  for (int k = 0; k < 8; ++k) acc[k] = fc_b[k * NH_ + lane];
  float accq = fc_b[NW_ - 1];

  const float4* xcq = (const float4*)(xc + us * NG_);
  const float4* wq4 = (const float4*)fc_w;
#pragma unroll
  for (int g4 = 0; g4 < NG_ / 4; ++g4) {
    const float4 xv = xcq[g4];
#pragma unroll
    for (int k = 0; k < 8; ++k) {
      const float4 w = wq4[(k * NH_ + lane) * (NG_ / 4) + g4];
      acc[k] = fmaf(xv.x, w.x, acc[k]);
      acc[k] = fmaf(xv.y, w.y, acc[k]);
      acc[k] = fmaf(xv.z, w.z, acc[k]);
      acc[k] = fmaf(xv.w, w.w, acc[k]);
    }
    {
      const float4 w = wq4[(NW_ - 1) * (NG_ / 4) + g4];
      accq = fmaf(xv.x, w.x, accq);
      accq = fmaf(xv.y, w.y, accq);
      accq = fmaf(xv.z, w.z, accq);
      accq = fmaf(xv.w, w.w, accq);
    }
  }

  // ---- gates (per-lane = per hidden unit)
  const float gm = expf(acc[0]) + 1.0f;
  const float ge = sigmoidf(acc[1]) * 2.0f;
  const float go = sigmoidf(acc[2]);
  const float gl = expf(acc[3] * 2.0f);
  float mx = acc[4];
#pragma unroll
  for (int mm = 32; mm >= 1; mm >>= 1) mx = fmaxf(mx, __shfl_xor(mx, mm, 64));
  const float ex = expf(acc[4] - mx);
  float sm = ex;
#pragma unroll
  for (int mm = 32; mm >= 1; mm >>= 1) sm += __shfl_xor(sm, mm, 64);
  const float ga = ex / sm;
  const float gb = sigmoidf(acc[5]);
  const float kb = sigmoidf(acc[6]) * 0.1f;
  const float gi = sigmoidf(acc[7]);
  const float qb = fmaxf(accq, 0.0f) * (1.0f / NH_);
  const float kb1m = 1.0f - kb;                 // G0n = G*(1-kb)
  const float nge  = -ge;
  const float gq1  = go * (1.0f - gb) - 1.0f;   // y = ga*(H + M*gq1 + G*kb)

  // ---- scan state
  float S0 = 0.0f, H0 = 0.0f, G0 = 0.0f;
  const int vofs = lane * NS_ + site;           // out index for t = c*64+lane

  // stage chunk-0 met (lane = timestep); in-order DS pipe, no barrier needed
  smet[wv][lane] = compute_met(xcur);

  // 18-VALU step; y via folded Q1+Q2+Q3
  auto step = [&](const float4 mt, float* ywaddr) {
    const float melt = mt.z * gm;                   // relu(Ta)*gm
    const float dmx  = fmaxf(S0 - melt, 0.0f);      // = S0 - Sm
    const float hs   = H0 + S0;                     // H0 + Sm = hs - dmx
    S0 = dmx + mt.x;                                // S0' = Ps + dmx
    const float t3 = fmaf(mt.y, gi, hs - dmx);      // + Pl*gi
    const float H  = fmaxf(fmaf(mt.w, nge, t3), 0.0f);
    const float M  = fminf(H, gl);
    const float Q2a = M * go;
    H0 = fminf(H - Q2a, gl);
    const float G = fmaf(Q2a, gb, G0);
    G0 = G * kb1m;
    *ywaddr = fmaf(G, kb, fmaf(M, gq1, H)) * ga;    // ga*(Q1+Q2+Q3)
  };

  // ---- peeled chunk 0 (no previous chunk to reduce)
  {
    float4 xnext = xp[(CH_ + lane) * NS_ + site];   // t = 64..127, in range
    float* yw = &ytile[wv][0][lane];
    const float4* mp = &smet[wv][0];
#pragma unroll
    for (int j = 0; j < CH_; ++j) step(mp[j], yw + j * YPAD_);
    smet[wv][lane] = compute_met(xnext);            // met for chunk 1
  }

  // ---- chunks 1..5: steps + interleaved reduction of chunk c-1
  for (int c = 1; c < NCHUNK_; ++c) {
    int tn = (c + 1) * CH_ + lane;                  // prefetch chunk c+1
    tn = (tn < NT_) ? tn : (NT_ - 1);               // clamp (c=4 tail, c=5 dummy)
    const float4 xnext = xp[tn * NS_ + site];

    float*       yw = &ytile[wv][c & 1][lane];
    const float* yr = &ytile[wv][(c - 1) & 1][lane * YPAD_];
    const float4* mp = &smet[wv][0];
    float r0 = 0.0f, r1 = 0.0f, r2 = 0.0f, r3 = 0.0f;
#pragma unroll
    for (int j = 0; j < CH_; ++j) {
      if ((j & 3) == 0) {                           // 16x per chunk: prev-row sums
        r0 += yr[j + 0];
        r1 += yr[j + 1];
        r2 += yr[j + 2];
        r3 += yr[j + 3];
      }
      step(mp[j], yw + j * YPAD_);
    }
    out[vofs + (c - 1) * CH_ * NS_] = ((r0 + r1) + (r2 + r3)) + qb;  // t<320 ✓
    smet[wv][lane] = compute_met(xnext);            // met for chunk c+1
  }

  // ---- epilogue: reduce chunk 5 (buffer 1); valid lanes t = 320+lane < 365
  {
    const float* yr = &ytile[wv][1][lane * YPAD_];
    float r0 = 0.0f, r1 = 0.0f, r2 = 0.0f, r3 = 0.0f;
#pragma unroll
    for (int h = 0; h < CH_; h += 4) {
      r0 += yr[h + 0];
      r1 += yr[h + 1];
      r2 += yr[h + 2];
      r3 += yr[h + 3];
    }
    if (lane < NT_ - 5 * CH_)                       // lane < 45
      out[vofs + 5 * CH_ * NS_] = ((r0 + r1) + (r2 + r3)) + qb;
  }
}

extern "C" void kernel_launch(void* const* d_in, const int* in_sizes, int n_in,
                              void* d_out, int out_size, void* d_ws, size_t ws_size,
                              hipStream_t stream) {
  const float* x    = (const float*)d_in[0];
  const float* xc   = (const float*)d_in[1];
  const float* fc_w = (const float*)d_in[2];
  const float* fc_b = (const float*)d_in[3];
  float* out = (float*)d_out;

  hipLaunchKernelGGL(waternet_scan, dim3(NS_ / 4), dim3(256), 0, stream,
                     x, xc, fc_w, fc_b, out);
}